// Round 12
// baseline (149.302 us; speedup 1.0000x reference)
//
#include <hip/hip_runtime.h>
#include <hip/hip_bf16.h>

typedef __attribute__((ext_vector_type(8))) short        short8;
typedef __attribute__((ext_vector_type(8))) __bf16       bf16x8;
typedef __attribute__((ext_vector_type(4))) float        f32x4;
typedef __attribute__((ext_vector_type(4))) unsigned int u32x4;

#define NB 32
#define CI 64
#define H  128
#define W  128
#define OH 126
#define OW 126
#define HW (H*W)

// bf16 LDS half-buffer (32 ci): [pix = r*66+col][32 ci][16B pad]
// RSTRIDE = 80 B/pix. b128 ops at stride 80: start banks 20*l mod 32 ->
// 8 windows x 8 lanes over the 8 min clocks -> near-conflict-free.
#define TCOLS 66
#define RSTRIDE 80
#define HBYTES (6*TCOLS*RSTRIDE)   // 31680 B; two buffers = 63360 -> 2 blocks/CU

__device__ __forceinline__ unsigned int f2bf(float f) {
    unsigned int u = __builtin_bit_cast(unsigned int, f);
    u += 0x7fffu + ((u >> 16) & 1u);
    return u >> 16;
}

// packed f32x2 -> bf16x2 (RNE), 1 instruction
__device__ __forceinline__ unsigned int cvt_pk(float lo, float hi) {
    unsigned int r;
    asm("v_cvt_pk_bf16_f32 %0, %1, %2" : "=v"(r) : "v"(lo), "v"(hi));
    return r;
}

// tanh(x) = 1 - 2/(exp2(2*log2e*x)+1); exact at +/-inf, ~1e-7 abs err
__device__ __forceinline__ float fast_tanh(float x) {
    float e = __builtin_amdgcn_exp2f(x * 2.8853900817779268f);
    float r = __builtin_amdgcn_rcpf(e + 1.0f);
    return 1.0f - 2.0f * r;
}

// ---------------------------------------------------------------------------
// Pre-pass: weights (64,64,3,3) fp32 OIHW -> MFMA B-fragment order, bf16.
// flat elem idx = ((ks*4 + cf)*64 + lane)*8 + j
//   ks = 0..17: khw = ks>>1, ci-half = ks&1; cf = co quarter,
//   lane: co = cf*16 + (lane&15), ci = (ks&1)*32 + 8*(lane>>4) + j
// ---------------------------------------------------------------------------
__global__ void wxform(const float* __restrict__ w, unsigned short* __restrict__ ws) {
    int tid = blockIdx.x * 256 + threadIdx.x;
    if (tid >= 18*4*64*8) return;
    int j   = tid & 7;
    int l   = (tid >> 3) & 63;
    int cf  = (tid >> 9) & 3;
    int ks  = tid >> 11;
    int co  = cf*16 + (l & 15);
    int ci  = (ks & 1)*32 + ((l >> 4) << 3) + j;
    int khw = ks >> 1;               // kh*3+kw
    int kh  = khw / 3, kw = khw % 3;
    float v = w[co*(CI*9) + ci*9 + kh*3 + kw];
    ws[tid] = (unsigned short)f2bf(v);
}

// Stage one ci-half (32 planes starting at xh) of the 6x66 tile into buf.
// 512 threads: 24 wave-tasks (row x quad-pair) = 3 iters/wave; lane = col.
__device__ __forceinline__ void stage_half(const float* __restrict__ xh,
                                           char* __restrict__ buf,
                                           int r0, int c0, int wv, int lane, int tid) {
    #pragma unroll
    for (int i = 0; i < 3; ++i) {
        const int task = wv + 8*i;           // 0..23
        const int r    = task >> 2;          // 0..5
        const int p    = task & 3;           // quad-pair (8 ci)
        const int gr   = r0 + r;
        float f0=0.f,f1=0.f,f2=0.f,f3=0.f,f4=0.f,f5=0.f,f6=0.f,f7=0.f;
        if (gr < H) {                         // wave-uniform; zero-fill OOB
            const float* xp = xh + (size_t)(p*8)*HW + gr*W + c0 + lane;
            f0 = xp[0];    f1 = xp[HW];   f2 = xp[2*HW]; f3 = xp[3*HW];
            f4 = xp[4*HW]; f5 = xp[5*HW]; f6 = xp[6*HW]; f7 = xp[7*HW];
        }
        u32x4 pk;
        pk.x = cvt_pk(f0, f1); pk.y = cvt_pk(f2, f3);
        pk.z = cvt_pk(f4, f5); pk.w = cvt_pk(f6, f7);
        *(u32x4*)(buf + (r*TCOLS + lane)*RSTRIDE + p*16) = pk;
    }
    // halo cols 64,65: threads 0..47 -> (row 0..5) x (col 2) x (pair 4)
    if (tid < 48) {
        const int r  = tid >> 3;
        const int cc = (tid >> 2) & 1;
        const int p  = tid & 3;
        const int gr = r0 + r;
        const int gc = c0 + 64 + cc;
        float f0=0.f,f1=0.f,f2=0.f,f3=0.f,f4=0.f,f5=0.f,f6=0.f,f7=0.f;
        if (gr < H && gc < W) {
            const float* xq = xh + (size_t)(p*8)*HW + gr*W + gc;
            f0 = xq[0];    f1 = xq[HW];   f2 = xq[2*HW]; f3 = xq[3*HW];
            f4 = xq[4*HW]; f5 = xq[5*HW]; f6 = xq[6*HW]; f7 = xq[7*HW];
        }
        u32x4 pk;
        pk.x = cvt_pk(f0, f1); pk.y = cvt_pk(f2, f3);
        pk.z = cvt_pk(f4, f5); pk.w = cvt_pk(f6, f7);
        *(u32x4*)(buf + (r*TCOLS + 64 + cc)*RSTRIDE + p*16) = pk;
    }
}

// Accumulate one ci-half: 9 khw x 2 m x 4 cf MFMAs from buf.
__device__ __forceinline__ void compute_half(const char* __restrict__ buf,
                                             const short8* __restrict__ wp,
                                             int cih, int abase, int lane,
                                             f32x4 acc[2][4]) {
    #pragma unroll
    for (int khw = 0; khw < 9; ++khw) {
        short8 wfb[4];
        #pragma unroll
        for (int cf = 0; cf < 4; ++cf)
            wfb[cf] = wp[((khw*2 + cih)*4 + cf)*64 + lane];
        const int kh = khw/3, kw = khw%3;
        #pragma unroll
        for (int m = 0; m < 2; ++m) {
            const short8 av = *(const short8*)(
                buf + abase + (kh*TCOLS + kw + m*16)*RSTRIDE);
            const bf16x8 a = __builtin_bit_cast(bf16x8, av);
            #pragma unroll
            for (int cf = 0; cf < 4; ++cf)
                acc[m][cf] = __builtin_amdgcn_mfma_f32_16x16x32_bf16(
                    a, __builtin_bit_cast(bf16x8, wfb[cf]), acc[m][cf], 0, 0, 0);
        }
    }
}

// ---------------------------------------------------------------------------
// Main: implicit-GEMM conv + channel-min + tanh(tanh()).
// In-block pipeline: each block owns (c0, r0) and iterates 4 batches x 2
// ci-halves, double-buffered LDS halves; stage(u+1) issued in the same
// basic block as compute(u) -> scheduler hides staging latency under MFMAs.
// ---------------------------------------------------------------------------
__global__ __launch_bounds__(512, 4)
void conv_min_tanh(const float* __restrict__ x,
                   const unsigned short* __restrict__ wfrag,
                   const float* __restrict__ bias,
                   float* __restrict__ out) {
    __shared__ __align__(16) char xs0[HBYTES];
    __shared__ __align__(16) char xs1[HBYTES];

    const int tid  = threadIdx.x;
    const int lane = tid & 63;
    const int wv   = tid >> 6;           // 0..7
    const int c0   = blockIdx.x * 64;    // ow base (0 or 64)
    const int r0   = blockIdx.y * 4;     // oh base
    const int bz   = blockIdx.z;         // batch quad

    const int lane_c = lane & 15;
    const int hi     = lane >> 4;
    const int wr     = wv >> 1;          // output row within tile (0..3)
    const int ch     = wv & 1;           // col half (0..1)
    const int orow   = r0 + wr;
    const bool live  = (orow < OH);      // wave-uniform

    const short8* wp = (const short8*)wfrag;
    const int abase  = (wr*TCOLS + ch*32 + lane_c)*RSTRIDE + hi*16;

    const float bs0 = bias[lane_c], bs1 = bias[16 + lane_c],
                bs2 = bias[32 + lane_c], bs3 = bias[48 + lane_c];

    // prologue: stage (t=0, cih=0)
    stage_half(x + (size_t)(bz*4)*CI*HW, xs0, r0, c0, wv, lane, tid);
    __syncthreads();

    #pragma unroll 1
    for (int t = 0; t < 4; ++t) {
        const int b = bz*4 + t;
        const float* xb = x + (size_t)b*CI*HW;

        f32x4 acc[2][4];
        #pragma unroll
        for (int m = 0; m < 2; ++m)
            #pragma unroll
            for (int cf = 0; cf < 4; ++cf)
                acc[m][cf] = (f32x4){0.f, 0.f, 0.f, 0.f};

        // unit A: stage (t, cih=1) -> xs1  ||  compute cih=0 from xs0
        stage_half(xb + (size_t)32*HW, xs1, r0, c0, wv, lane, tid);
        if (live) compute_half(xs0, wp, 0, abase, lane, acc);
        __syncthreads();

        // unit B: stage (t+1, cih=0) -> xs0  ||  compute cih=1 from xs1
        if (t < 3) stage_half(xb + (size_t)CI*HW, xs0, r0, c0, wv, lane, tid);
        if (live) {
            compute_half(xs1, wp, 1, abase, lane, acc);
            // epilogue for batch b: +bias, min over 64 co, tanh(tanh())
            float* outp = out + (size_t)(b*OH + orow)*OW;
            #pragma unroll
            for (int m = 0; m < 2; ++m) {
                #pragma unroll
                for (int rg = 0; rg < 4; ++rg) {
                    float v0 = fminf(fminf(acc[m][0][rg] + bs0, acc[m][1][rg] + bs1),
                                     fminf(acc[m][2][rg] + bs2, acc[m][3][rg] + bs3));
                    v0 = fminf(v0, __shfl_xor(v0, 1));
                    v0 = fminf(v0, __shfl_xor(v0, 2));
                    v0 = fminf(v0, __shfl_xor(v0, 4));
                    v0 = fminf(v0, __shfl_xor(v0, 8));
                    const float vt = fast_tanh(fast_tanh(v0));
                    const int ocol = c0 + ch*32 + m*16 + hi*4 + rg;
                    if (lane_c == 0 && ocol < OW) outp[ocol] = vt;
                }
            }
        }
        __syncthreads();
    }
}

extern "C" void kernel_launch(void* const* d_in, const int* in_sizes, int n_in,
                              void* d_out, int out_size, void* d_ws, size_t ws_size,
                              hipStream_t stream) {
    const float* x    = (const float*)d_in[0];
    const float* w    = (const float*)d_in[1];
    const float* bias = (const float*)d_in[2];
    float* out        = (float*)d_out;
    unsigned short* wbuf = (unsigned short*)d_ws;   // needs 73728 B

    wxform<<<dim3(144), dim3(256), 0, stream>>>(w, wbuf);
    conv_min_tanh<<<dim3(2, 32, 8), dim3(512), 0, stream>>>(x, wbuf, bias, out);
}